// Round 8
// baseline (582.748 us; speedup 1.0000x reference)
//
#include <hip/hip_runtime.h>
#include <cstdint>

// ---------------------------------------------------------------------------
// DND lookup: A=8, N=50000, D=64, B=256, K=50.
// Full path (workspace permitting):
//   K1: FUSED bf16-MFMA filter GEMM (R7's separate pack kernel K0b removed).
//       QT=256: one q-block per (a, n-slice) -> every key tile is read from
//       HBM exactly once, packed inline to MFMA fragment order (R5-verified
//       mapping), thresholds thr=(ksq-25)/2 via lane-pair shfl. A-frags for
//       all 256 queries live in 32 VGPRs/wave. Candidates staged in LDS
//       (per-b counters, SLOTS=20), bulk-flushed once per tile (R7 scheme).
//   K2: per-(a,b): integer-bin histogram superset (+4 bins = 1.0 d2 margin
//       for bf16 noise) -> bit-exact numpy-fp32-replica re-score/rank.
//   K3: max / first-argmax.
// Fallback path (small ws): R5 kernels verbatim (passed).
// Output layout (flat fp32): [0,256) max | [256,512) action | [512,2560)
// values_all | [2560,104960) idx | [104960,207360) scores.
// ---------------------------------------------------------------------------

#define A_N 8
#define N_N 50000
#define D_N 64
#define B_N 256
#define K_N 50

constexpr int   NBT = 128;                    // n rows per tile
constexpr int   NT  = (N_N + NBT - 1) / NBT;  // 391
constexpr int   SL  = 128;                    // full path: 128*8 = 1024 blocks
constexpr int   QTF = 64;                     // fallback q rows per block
constexpr int   SLF = 64;                     // fallback slices
constexpr int   SLOTS = 20;                   // LDS cand slots per b per iter
constexpr int   CAPMAX = 4096;
constexpr float TMARG = 25.0f;

constexpr int OFF_MAX = 0;
constexpr int OFF_ACT = 256;
constexpr int OFF_VAL = 512;
constexpr int OFF_IDX = 2560;
constexpr int OFF_SC  = 104960;

// ---- full-path workspace layout (bytes) ----
constexpr size_t WSN_CNT  = 0;          // 2048*4
constexpr size_t WSN_CAND = 8192;       // 2048*cap*4

// ---- fallback workspace layout ----
constexpr size_t WS_CNT  = 0;
constexpr size_t WS_QSQ  = 16384;
constexpr size_t WS_KSQ  = 17408;
constexpr size_t WS_CAND = 1617920;

typedef __attribute__((ext_vector_type(8))) short bf16x8;
typedef __attribute__((ext_vector_type(4))) float f32x4;

__device__ __forceinline__ unsigned bfr(float f)
{
    unsigned u = __float_as_uint(f);
    return (u + 0x7FFFu + ((u >> 16) & 1u)) >> 16;
}
__device__ __forceinline__ uint4 packbf8(const float* f)
{
    uint4 w;
    w.x = bfr(f[0]) | (bfr(f[1]) << 16);
    w.y = bfr(f[2]) | (bfr(f[3]) << 16);
    w.z = bfr(f[4]) | (bfr(f[5]) << 16);
    w.w = bfr(f[6]) | (bfr(f[7]) << 16);
    return w;
}

// ---------------------------------------------------------------------------
// numpy pairwise_sum replicas (bit-exact via _rn intrinsics).
// ---------------------------------------------------------------------------
__device__ __forceinline__ float np_tree8(const float r[8])
{
    return __fadd_rn(__fadd_rn(__fadd_rn(r[0], r[1]), __fadd_rn(r[2], r[3])),
                     __fadd_rn(__fadd_rn(r[4], r[5]), __fadd_rn(r[6], r[7])));
}

__device__ __forceinline__ float np_sumsq64(const float* __restrict__ a)
{
    float r[8];
#pragma unroll
    for (int j = 0; j < 8; ++j) r[j] = __fmul_rn(a[j], a[j]);
    for (int i = 8; i < 64; i += 8)
#pragma unroll
        for (int j = 0; j < 8; ++j)
            r[j] = __fadd_rn(r[j], __fmul_rn(a[i + j], a[i + j]));
    return np_tree8(r);
}

__device__ __forceinline__ float np_sum50(const float* __restrict__ a)
{
    float r[8];
#pragma unroll
    for (int j = 0; j < 8; ++j) r[j] = a[j];
    for (int i = 8; i < 48; i += 8)
#pragma unroll
        for (int j = 0; j < 8; ++j) r[j] = __fadd_rn(r[j], a[i + j]);
    float res = np_tree8(r);
    res = __fadd_rn(res, a[48]);
    res = __fadd_rn(res, a[49]);
    return res;
}

// ===========================================================================
// FULL PATH
// ===========================================================================

// LDS union: afrag lives only in the prologue; run-phase arrays reuse it.
union K1Smem {
    uint4 afrag[16][2][64];               // 32 KB  [qtile][kh][lane]
    struct {
        uint4    bfrag[16][64];           // 16 KB  [s*2+kh][lane]
        unsigned lbuf[B_N][SLOTS];        // 20 KB
        float    thrs[NBT];               // 0.5 KB
        int      lcnt[B_N];               // 1 KB
    } run;                                // 37.9 KB
};

// K1: fused pack + MFMA filter. Grid (SL, 1, A_N), 256 threads.
__global__ __launch_bounds__(256, 4)
void dnd_k1(const float* __restrict__ query, const float* __restrict__ keys,
            int* __restrict__ cnt, unsigned* __restrict__ cand, int cap)
{
    __shared__ K1Smem sm;

    const int a    = blockIdx.z;
    const int sl   = blockIdx.x;
    const int tid  = threadIdx.x;
    const int lane = tid & 63;
    const int wave = tid >> 6;
    const int quad = lane >> 4;
    const int nl   = lane & 15;

    // ---- prologue: stage ALL 256 q rows to fragment order (2 passes) ----
#pragma unroll
    for (int p = 0; p < 2; ++p) {
        const int r = tid >> 1, h = tid & 1;      // r 0..127, h = k-half
        const int row = p * 128 + r;
        const float4* s4 = (const float4*)(query + (size_t)row * D_N + h * 32);
        float4 fv[8];
#pragma unroll
        for (int i = 0; i < 8; ++i) fv[i] = s4[i];
        const float* f = (const float*)fv;
        const int qtile = row >> 4, m = row & 15;
#pragma unroll
        for (int g = 0; g < 4; ++g)               // k = h*32 + g*8 + j
            sm.afrag[qtile][h][g * 16 + m] = packbf8(f + g * 8);
    }
    __syncthreads();
    // each wave owns q-subtiles wave*4 .. wave*4+3
    bf16x8 aF[4][2];
#pragma unroll
    for (int qs = 0; qs < 4; ++qs)
#pragma unroll
        for (int kh = 0; kh < 2; ++kh)
            aF[qs][kh] = ((const bf16x8*)sm.afrag)[((wave * 4 + qs) * 2 + kh) * 64 + lane];
    __syncthreads();               // afrag reads complete -> union region free
    sm.run.lcnt[tid] = 0;          // own-thread read in first flush: no barrier

    for (int t = sl; t < NT; t += SL) {
        const int n0 = t * NBT;

        // ---- phase 1: flush-prev (lcnt/lbuf) + stage tile (bfrag/thrs) ----
        {
            int m2 = sm.run.lcnt[tid];            // prev MAC results (B2-safe)
            sm.run.lcnt[tid] = 0;
            if (m2 > SLOTS) m2 = SLOTS;
            if (m2 > 0) {
                const int gb = a * B_N + tid;
                const int base = atomicAdd(&cnt[gb], m2);
                unsigned* dst = cand + (size_t)gb * cap;
                for (int i = 0; i < m2; ++i) {
                    const int p = base + i;
                    if (p < cap) dst[p] = sm.run.lbuf[tid][i];
                }
            }
        }
        {
            const int r = tid >> 1, h = tid & 1;
            int n = n0 + r; if (n > N_N - 1) n = N_N - 1;   // clamp tail rows
            const float4* s4 = (const float4*)(keys + ((size_t)a * N_N + n) * D_N + h * 32);
            float4 fv[8];
#pragma unroll
            for (int i = 0; i < 8; ++i) fv[i] = s4[i];
            float ps = 0.f;
#pragma unroll
            for (int i = 0; i < 8; ++i)
                ps += fv[i].x * fv[i].x + fv[i].y * fv[i].y + fv[i].z * fv[i].z + fv[i].w * fv[i].w;
            const float* f = (const float*)fv;
            const int s = r >> 4, m = r & 15;
#pragma unroll
            for (int g = 0; g < 4; ++g)           // k = h*32 + g*8 + j
                sm.run.bfrag[s * 2 + h][g * 16 + m] = packbf8(f + g * 8);
            const float ks2 = ps + __shfl_xor(ps, 1, 64);   // pair-sum halves
            if (h == 0)
                sm.run.thrs[r] = (n0 + r < N_N) ? 0.5f * (ks2 - TMARG)
                                                : __builtin_huge_valf();
        }
        __syncthreads();   // B1: staging visible, lcnt reset visible

        // ---- phase 2: MAC + LDS candidate staging ----
#pragma unroll
        for (int s = 0; s < 8; ++s) {
            const bf16x8 b0 = ((const bf16x8*)sm.run.bfrag)[(s * 2 + 0) * 64 + lane];
            const bf16x8 b1 = ((const bf16x8*)sm.run.bfrag)[(s * 2 + 1) * 64 + lane];
            const int   nn  = n0 + s * 16 + nl;
            const float thr = sm.run.thrs[s * 16 + nl];
#pragma unroll
            for (int qs = 0; qs < 4; ++qs) {
                f32x4 c = {0.f, 0.f, 0.f, 0.f};
                c = __builtin_amdgcn_mfma_f32_16x16x32_bf16(aF[qs][0], b0, c, 0, 0, 0);
                c = __builtin_amdgcn_mfma_f32_16x16x32_bf16(aF[qs][1], b1, c, 0, 0, 0);
#pragma unroll
                for (int r = 0; r < 4; ++r) {
                    if (c[r] >= thr) {            // inf tail never passes
                        const int bl = (wave * 4 + qs) * 16 + quad * 4 + r;
                        const float d2rel = fmaf(-2.f, c[r], fmaf(2.f, thr, TMARG));
                        int qv = (int)fmaf(d2rel, 1000.f, 40000.f);
                        qv = qv < 0 ? 0 : (qv > 65535 ? 65535 : qv);
                        const unsigned entry = ((unsigned)qv << 16) | (unsigned)nn;
                        const int p = atomicAdd(&sm.run.lcnt[bl], 1);
                        if (p < SLOTS) sm.run.lbuf[bl][p] = entry;
                        else {                    // rare overflow: direct global
                            const int gb = a * B_N + bl;
                            const int gp = atomicAdd(&cnt[gb], 1);
                            if (gp < cap) cand[(size_t)gb * cap + gp] = entry;
                        }
                    }
                }
            }
        }
        __syncthreads();   // B2: lbuf/lcnt complete for next flush
    }

    // ---- final flush ----
    {
        int m2 = sm.run.lcnt[tid];
        if (m2 > SLOTS) m2 = SLOTS;
        if (m2 > 0) {
            const int gb = a * B_N + tid;
            const int base = atomicAdd(&cnt[gb], m2);
            unsigned* dst = cand + (size_t)gb * cap;
            for (int i = 0; i < m2; ++i) {
                const int p = base + i;
                if (p < cap) dst[p] = sm.run.lbuf[tid][i];
            }
        }
    }
}

// K2 (full): per-(a,b) np-fp32-replica top-50 + outputs (unchanged from R7).
__global__ __launch_bounds__(256)
void dnd_k2(const float* __restrict__ query, const float* __restrict__ keys,
            const float* __restrict__ values,
            const int* __restrict__ cnt, const unsigned* __restrict__ cand, int cap,
            float* __restrict__ dout)
{
    __shared__ __align__(16) float qrow[D_N];
    __shared__ int   hist[256];
    __shared__ float sdf[512];
    __shared__ int   sn[512];
    __shared__ int   wn[K_N];
    __shared__ float wsc[K_N];
    __shared__ float wgv[K_N];
    __shared__ int   nsurv;
    __shared__ int   bstar;
    __shared__ float qsq_np;

    const int b   = blockIdx.x;
    const int a   = blockIdx.y;
    const int ab  = a * B_N + b;
    const int tid = threadIdx.x;

    if (tid < D_N) qrow[tid] = query[(size_t)b * D_N + tid];
    hist[tid & 255] = 0;
    if (tid == 0) nsurv = 0;
    if (tid < K_N) wn[tid] = 0;
    __syncthreads();
    if (tid == 0) qsq_np = np_sumsq64(qrow);
    __syncthreads();

    int c = cnt[ab]; if (c > cap) c = cap;
    const unsigned* base = cand + (size_t)ab * cap;

    for (int i = tid; i < c; i += 256) {
        int bin = (int)(base[i] >> 16) / 250;
        bin = bin > 255 ? 255 : bin;
        atomicAdd(&hist[bin], 1);
    }
    __syncthreads();
    if (tid == 0) {
        const int need = c < K_N ? c : K_N;
        int cum = 0, bs = 255;
        for (int i = 0; i < 256; ++i) { cum += hist[i]; if (cum >= need) { bs = i; break; } }
        bstar = bs;
    }
    __syncthreads();
    const int bs = bstar + 4;   // +1.0 d2 margin under bf16 noise

    for (int i = tid; i < c; i += 256) {
        const unsigned e = base[i];
        int bin = (int)(e >> 16) / 250;
        bin = bin > 255 ? 255 : bin;
        if (bin <= bs) {
            int p = atomicAdd(&nsurv, 1);
            if (p < 512) sn[p] = (int)(e & 0xFFFFu);
        }
    }
    __syncthreads();
    int c2 = nsurv; if (c2 > 512) c2 = 512;

    const float qn = qsq_np;
    for (int i = tid; i < c2; i += 256) {
        const int n = sn[i];
        const float4* kr = (const float4*)(keys + ((size_t)a * N_N + n) * D_N);
        const float4* qr = (const float4*)qrow;
        float r[8];
#pragma unroll
        for (int j = 0; j < 8; ++j) r[j] = 0.f;
        float dot = 0.f;
#pragma unroll
        for (int cch = 0; cch < 16; ++cch) {
            float4 kk = kr[cch]; float4 qv = qr[cch];
            const int j0 = (cch & 1) * 4;
            if (cch < 2) {
                r[j0 + 0] = __fmul_rn(kk.x, kk.x);
                r[j0 + 1] = __fmul_rn(kk.y, kk.y);
                r[j0 + 2] = __fmul_rn(kk.z, kk.z);
                r[j0 + 3] = __fmul_rn(kk.w, kk.w);
            } else {
                r[j0 + 0] = __fadd_rn(r[j0 + 0], __fmul_rn(kk.x, kk.x));
                r[j0 + 1] = __fadd_rn(r[j0 + 1], __fmul_rn(kk.y, kk.y));
                r[j0 + 2] = __fadd_rn(r[j0 + 2], __fmul_rn(kk.z, kk.z));
                r[j0 + 3] = __fadd_rn(r[j0 + 3], __fmul_rn(kk.w, kk.w));
            }
            dot = __fmaf_rn(qv.x, kk.x, dot);
            dot = __fmaf_rn(qv.y, kk.y, dot);
            dot = __fmaf_rn(qv.z, kk.z, dot);
            dot = __fmaf_rn(qv.w, kk.w, dot);
        }
        const float ksq = np_tree8(r);
        sdf[i] = __fsub_rn(__fadd_rn(qn, ksq), __fmul_rn(2.0f, dot));
    }
    __syncthreads();

    for (int i = tid; i < c2; i += 256) {
        const float di = sdf[i]; const int ni = sn[i];
        int rank = 0;
        for (int j = 0; j < c2; ++j) {
            const float dj = sdf[j]; const int nj = sn[j];
            rank += (dj < di || (dj == di && nj < ni)) ? 1 : 0;
        }
        if (rank < K_N) wn[rank] = ni;
    }
    __syncthreads();

    if (tid < K_N) {
        const int n = wn[tid];
        const float* kr = keys + ((size_t)a * N_N + n) * D_N;
        float r[8];
#pragma unroll
        for (int j = 0; j < 8; ++j) {
            float d = __fsub_rn(qrow[j], kr[j]);
            r[j] = __fmul_rn(d, d);
        }
        for (int i = 8; i < 64; i += 8)
#pragma unroll
            for (int j = 0; j < 8; ++j) {
                float d = __fsub_rn(qrow[i + j], kr[i + j]);
                r[j] = __fadd_rn(r[j], __fmul_rn(d, d));
            }
        const float dist = np_tree8(r);
        wsc[tid] = dist;
        wgv[tid] = values[(size_t)a * N_N + n];
        dout[OFF_IDX + (size_t)(b * A_N + a) * K_N + tid] = (float)n;
        dout[OFF_SC  + (size_t)(b * A_N + a) * K_N + tid] = dist;
    }
    __syncthreads();

    if (tid == 0) {
        float w[K_N], wv[K_N];
#pragma unroll
        for (int k = 0; k < K_N; ++k) {
            w[k]  = __fdiv_rn(1.0f, __fadd_rn(wsc[k], 0.001f));
            wv[k] = __fmul_rn(w[k], wgv[k]);
        }
        dout[OFF_VAL + b * A_N + a] = __fdiv_rn(np_sum50(wv), np_sum50(w));
    }
}

__global__ void dnd_k3(float* __restrict__ dout)
{
    const int b = threadIdx.x;
    float best = -__builtin_huge_valf(); int bi = 0;
#pragma unroll
    for (int a = 0; a < A_N; ++a) {
        const float v = dout[OFF_VAL + b * A_N + a];
        if (v > best) { best = v; bi = a; }
    }
    dout[OFF_MAX + b] = best;
    dout[OFF_ACT + b] = (float)bi;
}

// ===========================================================================
// FALLBACK PATH — R5 kernels verbatim (passed).
// ===========================================================================

__global__ __launch_bounds__(256)
void dnd_k0f(const float* __restrict__ query, const float* __restrict__ keys,
             float* __restrict__ qsq_g, float* __restrict__ ksq_g)
{
    const int r = blockIdx.x * 256 + threadIdx.x;
    if (r >= A_N * N_N + B_N) return;
    const bool isk = r < A_N * N_N;
    const float4* s4 = (const float4*)(isk ? (keys + (size_t)r * D_N)
                                           : (query + (size_t)(r - A_N * N_N) * D_N));
    float s = 0.f;
#pragma unroll
    for (int i = 0; i < 16; ++i) {
        float4 v = s4[i];
        s += v.x * v.x + v.y * v.y + v.z * v.z + v.w * v.w;
    }
    if (isk) ksq_g[r] = s; else qsq_g[r - A_N * N_N] = s;
}

__global__ __launch_bounds__(256, 4)
void dnd_k1f(const float* __restrict__ query, const float* __restrict__ keys,
             const float* __restrict__ qsq_g, const float* __restrict__ ksq_g,
             int* __restrict__ cnt, uint2* __restrict__ cand, int cap)
{
    __shared__ __align__(16) uint4 afrag[4][2][64];
    __shared__ __align__(16) uint4 bfrag[8][2][64];
    __shared__ float qsqs[QTF];
    __shared__ float ksqs[NBT];

    const int a    = blockIdx.z;
    const int q0   = blockIdx.y * QTF;
    const int sl   = blockIdx.x;
    const int tid  = threadIdx.x;
    const int lane = tid & 63;
    const int wave = tid >> 6;
    const int quad = lane >> 4;
    const int nl   = lane & 15;

    {
        const int r = tid & 63, seg = tid >> 6;
        const float4* s4 = (const float4*)(query + (size_t)(q0 + r) * D_N + seg * 16);
        float4 fv[4];
#pragma unroll
        for (int i = 0; i < 4; ++i) fv[i] = s4[i];
        const float* f = (const float*)fv;
        const int qtile = r >> 4, m = r & 15, kh = seg >> 1;
        const int quadA = (seg & 1) * 2;
        afrag[qtile][kh][quadA * 16 + m]       = packbf8(f);
        afrag[qtile][kh][(quadA + 1) * 16 + m] = packbf8(f + 8);
    }
    if (tid < QTF) qsqs[tid] = qsq_g[q0 + tid];

    for (int t = sl; t < NT; t += SLF) {
        const int n0 = t * NBT;
        __syncthreads();
        {
            const int r = tid >> 1, h = tid & 1;
            int n = n0 + r; if (n > N_N - 1) n = N_N - 1;
            const float4* s4 = (const float4*)(keys + ((size_t)a * N_N + n) * D_N + h * 32);
            float4 fv[8];
#pragma unroll
            for (int i = 0; i < 8; ++i) fv[i] = s4[i];
            const float* f = (const float*)fv;
            const int s = r >> 4, m = r & 15;
#pragma unroll
            for (int g = 0; g < 4; ++g)
                bfrag[s][h][g * 16 + m] = packbf8(f + g * 8);
        }
        if (tid < NBT)
            ksqs[tid] = (n0 + tid < N_N) ? ksq_g[(size_t)a * N_N + n0 + tid]
                                         : __builtin_huge_valf();
        __syncthreads();

        const bf16x8 aA = ((const bf16x8*)afrag)[(wave * 2 + 0) * 64 + lane];
        const bf16x8 aB = ((const bf16x8*)afrag)[(wave * 2 + 1) * 64 + lane];

#pragma unroll
        for (int s = 0; s < 8; ++s) {
            const bf16x8 b0 = ((const bf16x8*)bfrag)[(s * 2 + 0) * 64 + lane];
            const bf16x8 b1 = ((const bf16x8*)bfrag)[(s * 2 + 1) * 64 + lane];
            f32x4 c = {0.f, 0.f, 0.f, 0.f};
            c = __builtin_amdgcn_mfma_f32_16x16x32_bf16(aA, b0, c, 0, 0, 0);
            c = __builtin_amdgcn_mfma_f32_16x16x32_bf16(aB, b1, c, 0, 0, 0);

            const int   nn  = n0 + s * 16 + nl;
            const float ksq = ksqs[s * 16 + nl];
#pragma unroll
            for (int r = 0; r < 4; ++r) {
                const int   qr = wave * 16 + quad * 4 + r;
                const float qq = qsqs[qr];
                const float d2 = qq + ksq - 2.0f * c[r];
                if (d2 <= qq + TMARG) {
                    const int b = q0 + qr;
                    const int p = atomicAdd(&cnt[a * B_N + b], 1);
                    if (p < cap) {
                        uint2 e; e.x = __float_as_uint(d2); e.y = (unsigned)nn;
                        cand[(size_t)(a * B_N + b) * cap + p] = e;
                    }
                }
            }
        }
    }
}

__global__ __launch_bounds__(256, 2)
void dnd_k2f(const float* __restrict__ query, const float* __restrict__ keys,
             const float* __restrict__ values,
             const int* __restrict__ cnt, const uint2* __restrict__ cand, int cap,
             float* __restrict__ dout)
{
    __shared__ __align__(16) float qrow[D_N];
    __shared__ float cd[CAPMAX];
    __shared__ int   cn[CAPMAX];
    __shared__ int   hist[256];
    __shared__ float sdf[512];
    __shared__ int   sn[512];
    __shared__ int   wn[K_N];
    __shared__ float wsc[K_N];
    __shared__ float wgv[K_N];
    __shared__ int   nsurv;
    __shared__ int   bstar;
    __shared__ float sqsq;
    __shared__ float qsq_np;

    const int b   = blockIdx.x;
    const int a   = blockIdx.y;
    const int ab  = a * B_N + b;
    const int tid = threadIdx.x;

    if (tid < D_N) qrow[tid] = query[(size_t)b * D_N + tid];
    hist[tid & 255] = 0;
    if (tid == 0) nsurv = 0;
    if (tid < K_N) wn[tid] = 0;
    __syncthreads();
    if (tid < 64) {
        float v = qrow[tid];
        float s = v * v;
#pragma unroll
        for (int m = 1; m < 64; m <<= 1) s += __shfl_xor(s, m, 64);
        if (tid == 0) sqsq = s;
    }
    if (tid == 0) qsq_np = np_sumsq64(qrow);
    __syncthreads();

    int c = cnt[ab]; if (c > cap) c = cap; if (c > CAPMAX) c = CAPMAX;
    const float qq = sqsq;

    for (int i = tid; i < c; i += 256) {
        uint2 e = cand[(size_t)ab * cap + i];
        float d = __uint_as_float(e.x);
        cd[i] = d; cn[i] = (int)e.y;
        int bin = (int)((d - qq + 40.f) * 4.f);
        bin = bin < 0 ? 0 : (bin > 255 ? 255 : bin);
        atomicAdd(&hist[bin], 1);
    }
    __syncthreads();
    if (tid == 0) {
        const int need = c < K_N ? c : K_N;
        int cum = 0, bs = 255;
        for (int i = 0; i < 256; ++i) { cum += hist[i]; if (cum >= need) { bs = i; break; } }
        bstar = bs;
    }
    __syncthreads();
    const int bs = bstar + 4;

    for (int i = tid; i < c; i += 256) {
        float d = cd[i];
        int bin = (int)((d - qq + 40.f) * 4.f);
        bin = bin < 0 ? 0 : (bin > 255 ? 255 : bin);
        if (bin <= bs) {
            int p = atomicAdd(&nsurv, 1);
            if (p < 512) sn[p] = cn[i];
        }
    }
    __syncthreads();
    int c2 = nsurv; if (c2 > 512) c2 = 512;

    const float qn = qsq_np;
    for (int i = tid; i < c2; i += 256) {
        const int n = sn[i];
        const float4* kr = (const float4*)(keys + ((size_t)a * N_N + n) * D_N);
        const float4* qr = (const float4*)qrow;
        float r[8];
#pragma unroll
        for (int j = 0; j < 8; ++j) r[j] = 0.f;
        float dot = 0.f;
#pragma unroll
        for (int cch = 0; cch < 16; ++cch) {
            float4 kk = kr[cch]; float4 qv = qr[cch];
            const int j0 = (cch & 1) * 4;
            if (cch < 2) {
                r[j0 + 0] = __fmul_rn(kk.x, kk.x);
                r[j0 + 1] = __fmul_rn(kk.y, kk.y);
                r[j0 + 2] = __fmul_rn(kk.z, kk.z);
                r[j0 + 3] = __fmul_rn(kk.w, kk.w);
            } else {
                r[j0 + 0] = __fadd_rn(r[j0 + 0], __fmul_rn(kk.x, kk.x));
                r[j0 + 1] = __fadd_rn(r[j0 + 1], __fmul_rn(kk.y, kk.y));
                r[j0 + 2] = __fadd_rn(r[j0 + 2], __fmul_rn(kk.z, kk.z));
                r[j0 + 3] = __fadd_rn(r[j0 + 3], __fmul_rn(kk.w, kk.w));
            }
            dot = __fmaf_rn(qv.x, kk.x, dot);
            dot = __fmaf_rn(qv.y, kk.y, dot);
            dot = __fmaf_rn(qv.z, kk.z, dot);
            dot = __fmaf_rn(qv.w, kk.w, dot);
        }
        const float ksq = np_tree8(r);
        sdf[i] = __fsub_rn(__fadd_rn(qn, ksq), __fmul_rn(2.0f, dot));
    }
    __syncthreads();

    for (int i = tid; i < c2; i += 256) {
        const float di = sdf[i]; const int ni = sn[i];
        int rank = 0;
        for (int j = 0; j < c2; ++j) {
            const float dj = sdf[j]; const int nj = sn[j];
            rank += (dj < di || (dj == di && nj < ni)) ? 1 : 0;
        }
        if (rank < K_N) wn[rank] = ni;
    }
    __syncthreads();

    if (tid < K_N) {
        const int n = wn[tid];
        const float* kr = keys + ((size_t)a * N_N + n) * D_N;
        float r[8];
#pragma unroll
        for (int j = 0; j < 8; ++j) {
            float d = __fsub_rn(qrow[j], kr[j]);
            r[j] = __fmul_rn(d, d);
        }
        for (int i = 8; i < 64; i += 8)
#pragma unroll
            for (int j = 0; j < 8; ++j) {
                float d = __fsub_rn(qrow[i + j], kr[i + j]);
                r[j] = __fadd_rn(r[j], __fmul_rn(d, d));
            }
        const float dist = np_tree8(r);
        wsc[tid] = dist;
        wgv[tid] = values[(size_t)a * N_N + n];
        dout[OFF_IDX + (size_t)(b * A_N + a) * K_N + tid] = (float)n;
        dout[OFF_SC  + (size_t)(b * A_N + a) * K_N + tid] = dist;
    }
    __syncthreads();

    if (tid == 0) {
        float w[K_N], wv[K_N];
#pragma unroll
        for (int k = 0; k < K_N; ++k) {
            w[k]  = __fdiv_rn(1.0f, __fadd_rn(wsc[k], 0.001f));
            wv[k] = __fmul_rn(w[k], wgv[k]);
        }
        dout[OFF_VAL + b * A_N + a] = __fdiv_rn(np_sum50(wv), np_sum50(w));
    }
}

// ===========================================================================
extern "C" void kernel_launch(void* const* d_in, const int* in_sizes, int n_in,
                              void* d_out, int out_size, void* d_ws, size_t ws_size,
                              hipStream_t stream)
{
    (void)in_sizes; (void)n_in; (void)out_size;
    const float* query  = (const float*)d_in[0];
    const float* keys   = (const float*)d_in[1];
    const float* values = (const float*)d_in[2];
    float* dout = (float*)d_out;
    char*  ws   = (char*)d_ws;

    long long capf = 0;
    if (ws_size > WSN_CAND)
        capf = (long long)((ws_size - WSN_CAND) / ((size_t)A_N * B_N * 4));
    const bool full = capf >= 3072;

    if (full) {
        int cap = capf > CAPMAX ? CAPMAX : (int)capf;
        int*      cnt  = (int*)(ws + WSN_CNT);
        unsigned* cand = (unsigned*)(ws + WSN_CAND);

        hipMemsetAsync(cnt, 0, A_N * B_N * sizeof(int), stream);
        dim3 g1(SL, 1, A_N);
        dnd_k1<<<g1, 256, 0, stream>>>(query, keys, cnt, cand, cap);
        dim3 g2(B_N, A_N);
        dnd_k2<<<g2, 256, 0, stream>>>(query, keys, values, cnt, cand, cap, dout);
        dnd_k3<<<1, 256, 0, stream>>>(dout);
    } else {
        int*   cnt   = (int*)(ws + WS_CNT);
        float* qsq_g = (float*)(ws + WS_QSQ);
        float* ksq_g = (float*)(ws + WS_KSQ);
        uint2* cand  = (uint2*)(ws + WS_CAND);
        int cap = CAPMAX;
        if (ws_size > WS_CAND) {
            size_t avail = (ws_size - WS_CAND) / ((size_t)A_N * B_N * 8);
            if ((size_t)cap > avail) cap = (int)avail;
        }
        if (cap < 1) cap = 1;

        hipMemsetAsync(cnt, 0, A_N * B_N * sizeof(int), stream);
        dnd_k0f<<<(A_N * N_N + B_N + 255) / 256, 256, 0, stream>>>(query, keys, qsq_g, ksq_g);
        dim3 g1(SLF, 4, A_N);
        dnd_k1f<<<g1, 256, 0, stream>>>(query, keys, qsq_g, ksq_g, cnt, cand, cap);
        dim3 g2(B_N, A_N);
        dnd_k2f<<<g2, 256, 0, stream>>>(query, keys, values, cnt, cand, cap, dout);
        dnd_k3<<<1, 256, 0, stream>>>(dout);
    }
}

// Round 9
// 272.274 us; speedup vs baseline: 2.1403x; 2.1403x over previous
//
#include <hip/hip_runtime.h>
#include <cstdint>

// ---------------------------------------------------------------------------
// DND lookup: A=8, N=50000, D=64, B=256, K=50.
// R9 = R7 revert (R8's QT=256 fusion spilled to scratch: WRITE 295 MB,
// VALU 5.6%, 437us) + one isolated tweak: K1 flushes LDS candidates every
// 2nd tile (SLOTS 24), skipping the post-MAC barrier on non-flush iters.
// Full path:
//   K0b: pack keys -> global bf16 fragment-order image kbf (51 MB) + dot
//        thresholds thr_n=(ksq-25)/2; zeroes cnt. kbf->K1 flows through L3.
//   K1:  MFMA filter GEMM; B-tiles staged via global_load_lds width-16 (no
//        staging VGPRs; 44 VGPR healthy); LDS candidate staging per b,
//        bulk-flushed every 2 tiles with one global atomic per b.
//   K2:  per-(a,b): integer-bin histogram superset (+4 bins = 1.0 d2 margin
//        for bf16 noise) -> bit-exact numpy-fp32-replica re-score/rank.
//   K3:  max / first-argmax.
// Fallback path (small ws): R5 kernels verbatim (passed).
// Output layout (flat fp32): [0,256) max | [256,512) action | [512,2560)
// values_all | [2560,104960) idx | [104960,207360) scores.
// ---------------------------------------------------------------------------

#define A_N 8
#define N_N 50000
#define D_N 64
#define B_N 256
#define K_N 50

constexpr int   QT  = 64;                     // q rows per block (full K1)
constexpr int   NBT = 128;                    // n rows per tile
constexpr int   NT  = (N_N + NBT - 1) / NBT;  // 391
constexpr int   SL  = 40;                     // full path: 40*4*8=1280 = 5/CU
constexpr int   SLF = 64;                     // fallback slices
constexpr int   SLOTS = 24;                   // LDS cand slots per b (2 tiles)
constexpr int   CAPMAX = 4096;
constexpr float TMARG = 25.0f;
constexpr int   NPAD = NT * NBT;              // 50048

constexpr int OFF_MAX = 0;
constexpr int OFF_ACT = 256;
constexpr int OFF_VAL = 512;
constexpr int OFF_IDX = 2560;
constexpr int OFF_SC  = 104960;

// ---- full-path workspace layout (bytes) ----
constexpr size_t WSF_CNT  = 0;                         // 2048*4
constexpr size_t WSF_THR  = 8192;                      // 8*50048*4
constexpr size_t WSF_KBF  = 1609728;                   // 8*391*16384
constexpr size_t WSF_CAND = 52858880;                  // 2048*cap*4

// ---- fallback workspace layout ----
constexpr size_t WS_CNT  = 0;
constexpr size_t WS_QSQ  = 16384;
constexpr size_t WS_KSQ  = 17408;
constexpr size_t WS_CAND = 1617920;

typedef __attribute__((ext_vector_type(8))) short bf16x8;
typedef __attribute__((ext_vector_type(4))) float f32x4;

__device__ __forceinline__ unsigned bfr(float f)
{
    unsigned u = __float_as_uint(f);
    return (u + 0x7FFFu + ((u >> 16) & 1u)) >> 16;
}
__device__ __forceinline__ uint4 packbf8(const float* f)
{
    uint4 w;
    w.x = bfr(f[0]) | (bfr(f[1]) << 16);
    w.y = bfr(f[2]) | (bfr(f[3]) << 16);
    w.z = bfr(f[4]) | (bfr(f[5]) << 16);
    w.w = bfr(f[6]) | (bfr(f[7]) << 16);
    return w;
}

__device__ __forceinline__ void async16(void* lds, const void* g)
{
    __builtin_amdgcn_global_load_lds(
        (const __attribute__((address_space(1))) void*)g,
        (__attribute__((address_space(3))) void*)lds, 16, 0, 0);
}

// ---------------------------------------------------------------------------
// numpy pairwise_sum replicas (bit-exact via _rn intrinsics).
// ---------------------------------------------------------------------------
__device__ __forceinline__ float np_tree8(const float r[8])
{
    return __fadd_rn(__fadd_rn(__fadd_rn(r[0], r[1]), __fadd_rn(r[2], r[3])),
                     __fadd_rn(__fadd_rn(r[4], r[5]), __fadd_rn(r[6], r[7])));
}

__device__ __forceinline__ float np_sumsq64(const float* __restrict__ a)
{
    float r[8];
#pragma unroll
    for (int j = 0; j < 8; ++j) r[j] = __fmul_rn(a[j], a[j]);
    for (int i = 8; i < 64; i += 8)
#pragma unroll
        for (int j = 0; j < 8; ++j)
            r[j] = __fadd_rn(r[j], __fmul_rn(a[i + j], a[i + j]));
    return np_tree8(r);
}

__device__ __forceinline__ float np_sum50(const float* __restrict__ a)
{
    float r[8];
#pragma unroll
    for (int j = 0; j < 8; ++j) r[j] = a[j];
    for (int i = 8; i < 48; i += 8)
#pragma unroll
        for (int j = 0; j < 8; ++j) r[j] = __fadd_rn(r[j], a[i + j]);
    float res = np_tree8(r);
    res = __fadd_rn(res, a[48]);
    res = __fadd_rn(res, a[49]);
    return res;
}

// ===========================================================================
// FULL PATH
// ===========================================================================

__global__ __launch_bounds__(256)
void dnd_k0b(const float* __restrict__ keys, float* __restrict__ thrn,
             uint4* __restrict__ kbf, int* __restrict__ cnt)
{
    __shared__ float khalf[NBT][2];
    const int t   = blockIdx.x;
    const int a   = blockIdx.y;
    const int tid = threadIdx.x;
    const int r   = tid >> 1, h = tid & 1;

    int n = t * NBT + r; if (n > N_N - 1) n = N_N - 1;
    const float4* s4 = (const float4*)(keys + ((size_t)a * N_N + n) * D_N + h * 32);
    float4 fv[8];
#pragma unroll
    for (int i = 0; i < 8; ++i) fv[i] = s4[i];
    float ps = 0.f;
#pragma unroll
    for (int i = 0; i < 8; ++i)
        ps += fv[i].x * fv[i].x + fv[i].y * fv[i].y + fv[i].z * fv[i].z + fv[i].w * fv[i].w;
    khalf[r][h] = ps;

    const float* f = (const float*)fv;
    const int s = r >> 4, m = r & 15;
    uint4* dst = kbf + ((size_t)(a * NT + t) * 16 + (s * 2 + h)) * 64;
#pragma unroll
    for (int g = 0; g < 4; ++g) dst[g * 16 + m] = packbf8(f + g * 8);

    __syncthreads();
    if (tid < NBT) {
        const int nn = t * NBT + tid;
        float thr = __builtin_huge_valf();
        if (nn < N_N) {
            const float ks = khalf[tid][0] + khalf[tid][1];
            thr = 0.5f * (ks - TMARG);                // dot >= thr <=> d2 <= qq+25
        }
        thrn[(size_t)a * NPAD + t * NBT + tid] = thr;
    }
    if (t == 0) cnt[a * B_N + tid] = 0;
}

// K1: MFMA filter; LDS-staged candidates, bulk flush every 2 tiles.
__global__ __launch_bounds__(256, 5)
void dnd_k1(const float* __restrict__ query, const uint4* __restrict__ kbf,
            const float* __restrict__ thrn,
            int* __restrict__ cnt, unsigned* __restrict__ cand, int cap)
{
    __shared__ __align__(16) uint4 afrag[4][2][64];   // 8 KB
    __shared__ __align__(16) uint4 bfrag[16][64];     // 16 KB
    __shared__ float    thrs[NBT];
    __shared__ int      lcnt[QT];                     // per-b LDS counters
    __shared__ unsigned lbuf[QT][SLOTS];              // 6 KB

    const int a    = blockIdx.z;
    const int q0   = blockIdx.y * QT;
    const int sl   = blockIdx.x;
    const int tid  = threadIdx.x;
    const int lane = tid & 63;
    const int wave = tid >> 6;
    const int quad = lane >> 4;
    const int nl   = lane & 15;

    // stage Q tile once (mapping verified R5-R7)
    {
        const int r = tid & 63, seg = tid >> 6;
        const float4* s4 = (const float4*)(query + (size_t)(q0 + r) * D_N + seg * 16);
        float4 fv[4];
#pragma unroll
        for (int i = 0; i < 4; ++i) fv[i] = s4[i];
        const float* f = (const float*)fv;
        const int qtile = r >> 4, m = r & 15, kh = seg >> 1;
        const int quadA = (seg & 1) * 2;
        afrag[qtile][kh][quadA * 16 + m]       = packbf8(f);
        afrag[qtile][kh][(quadA + 1) * 16 + m] = packbf8(f + 8);
    }
    if (tid < QT) lcnt[tid] = 0;
    __syncthreads();
    const bf16x8 aA = ((const bf16x8*)afrag)[(wave * 2 + 0) * 64 + lane];
    const bf16x8 aB = ((const bf16x8*)afrag)[(wave * 2 + 1) * 64 + lane];

    int it = 0;
    for (int t = sl; t < NT; t += SL, ++it) {
        const int n0 = t * NBT;
        __syncthreads();   // prev-iter bfrag/lbuf readers done
        {
            const char* src = (const char*)(kbf + (size_t)(a * NT + t) * 1024);
#pragma unroll
            for (int i = 0; i < 4; ++i) {
                const int off = i * 4096 + tid * 16;
                async16((char*)bfrag + off, src + off);
            }
        }
        if (tid < NBT) thrs[tid] = thrn[(size_t)a * NPAD + n0 + tid];
        __syncthreads();   // DMA drained + thrs visible

#pragma unroll
        for (int s = 0; s < 8; ++s) {
            const bf16x8 b0 = ((const bf16x8*)bfrag)[(s * 2 + 0) * 64 + lane];
            const bf16x8 b1 = ((const bf16x8*)bfrag)[(s * 2 + 1) * 64 + lane];
            f32x4 c = {0.f, 0.f, 0.f, 0.f};
            c = __builtin_amdgcn_mfma_f32_16x16x32_bf16(aA, b0, c, 0, 0, 0);
            c = __builtin_amdgcn_mfma_f32_16x16x32_bf16(aB, b1, c, 0, 0, 0);

            const int   nn  = n0 + s * 16 + nl;
            const float thr = thrs[s * 16 + nl];
#pragma unroll
            for (int r = 0; r < 4; ++r) {
                if (c[r] >= thr) {                    // inf tail never passes
                    const int bl = wave * 16 + quad * 4 + r;   // local b
                    const float d2rel = fmaf(-2.f, c[r], fmaf(2.f, thr, TMARG));
                    int qv = (int)fmaf(d2rel, 1000.f, 40000.f);
                    qv = qv < 0 ? 0 : (qv > 65535 ? 65535 : qv);
                    const unsigned entry = ((unsigned)qv << 16) | (unsigned)nn;
                    const int p = atomicAdd(&lcnt[bl], 1);     // LDS atomic
                    if (p < SLOTS) lbuf[bl][p] = entry;
                    else {                                      // rare overflow
                        const int gb = a * B_N + q0 + bl;
                        const int gp = atomicAdd(&cnt[gb], 1);
                        if (gp < cap) cand[(size_t)gb * cap + gp] = entry;
                    }
                }
            }
        }

        // flush every 2nd tile (and on this block's last tile). Condition is
        // block-uniform -> barrier inside is legal.
        const bool last = (t + SL >= NT);
        if ((it & 1) || last) {
            __syncthreads();   // all lbuf writes done
            if (tid < QT) {
                int m = lcnt[tid]; lcnt[tid] = 0;
                if (m > SLOTS) m = SLOTS;
                if (m > 0) {
                    const int gb = a * B_N + q0 + tid;
                    const int base = atomicAdd(&cnt[gb], m);  // ONE atomic per b
                    unsigned* dst = cand + (size_t)gb * cap;
                    for (int i = 0; i < m; ++i) {
                        const int p = base + i;
                        if (p < cap) dst[p] = lbuf[tid][i];
                    }
                }
            }
        }
    }
}

// K2 (full): per-(a,b) np-fp32-replica top-50 + outputs (R7 verbatim).
__global__ __launch_bounds__(256)
void dnd_k2(const float* __restrict__ query, const float* __restrict__ keys,
            const float* __restrict__ values,
            const int* __restrict__ cnt, const unsigned* __restrict__ cand, int cap,
            float* __restrict__ dout)
{
    __shared__ __align__(16) float qrow[D_N];
    __shared__ int   hist[256];
    __shared__ float sdf[512];
    __shared__ int   sn[512];
    __shared__ int   wn[K_N];
    __shared__ float wsc[K_N];
    __shared__ float wgv[K_N];
    __shared__ int   nsurv;
    __shared__ int   bstar;
    __shared__ float qsq_np;

    const int b   = blockIdx.x;
    const int a   = blockIdx.y;
    const int ab  = a * B_N + b;
    const int tid = threadIdx.x;

    if (tid < D_N) qrow[tid] = query[(size_t)b * D_N + tid];
    hist[tid & 255] = 0;
    if (tid == 0) nsurv = 0;
    if (tid < K_N) wn[tid] = 0;
    __syncthreads();
    if (tid == 0) qsq_np = np_sumsq64(qrow);
    __syncthreads();

    int c = cnt[ab]; if (c > cap) c = cap;
    const unsigned* base = cand + (size_t)ab * cap;

    for (int i = tid; i < c; i += 256) {
        int bin = (int)(base[i] >> 16) / 250;
        bin = bin > 255 ? 255 : bin;
        atomicAdd(&hist[bin], 1);
    }
    __syncthreads();
    if (tid == 0) {
        const int need = c < K_N ? c : K_N;
        int cum = 0, bs = 255;
        for (int i = 0; i < 256; ++i) { cum += hist[i]; if (cum >= need) { bs = i; break; } }
        bstar = bs;
    }
    __syncthreads();
    const int bs = bstar + 4;   // +1.0 d2 margin under bf16 noise

    for (int i = tid; i < c; i += 256) {
        const unsigned e = base[i];
        int bin = (int)(e >> 16) / 250;
        bin = bin > 255 ? 255 : bin;
        if (bin <= bs) {
            int p = atomicAdd(&nsurv, 1);
            if (p < 512) sn[p] = (int)(e & 0xFFFFu);
        }
    }
    __syncthreads();
    int c2 = nsurv; if (c2 > 512) c2 = 512;

    const float qn = qsq_np;
    for (int i = tid; i < c2; i += 256) {
        const int n = sn[i];
        const float4* kr = (const float4*)(keys + ((size_t)a * N_N + n) * D_N);
        const float4* qr = (const float4*)qrow;
        float r[8];
#pragma unroll
        for (int j = 0; j < 8; ++j) r[j] = 0.f;
        float dot = 0.f;
#pragma unroll
        for (int cch = 0; cch < 16; ++cch) {
            float4 kk = kr[cch]; float4 qv = qr[cch];
            const int j0 = (cch & 1) * 4;
            if (cch < 2) {
                r[j0 + 0] = __fmul_rn(kk.x, kk.x);
                r[j0 + 1] = __fmul_rn(kk.y, kk.y);
                r[j0 + 2] = __fmul_rn(kk.z, kk.z);
                r[j0 + 3] = __fmul_rn(kk.w, kk.w);
            } else {
                r[j0 + 0] = __fadd_rn(r[j0 + 0], __fmul_rn(kk.x, kk.x));
                r[j0 + 1] = __fadd_rn(r[j0 + 1], __fmul_rn(kk.y, kk.y));
                r[j0 + 2] = __fadd_rn(r[j0 + 2], __fmul_rn(kk.z, kk.z));
                r[j0 + 3] = __fadd_rn(r[j0 + 3], __fmul_rn(kk.w, kk.w));
            }
            dot = __fmaf_rn(qv.x, kk.x, dot);
            dot = __fmaf_rn(qv.y, kk.y, dot);
            dot = __fmaf_rn(qv.z, kk.z, dot);
            dot = __fmaf_rn(qv.w, kk.w, dot);
        }
        const float ksq = np_tree8(r);
        sdf[i] = __fsub_rn(__fadd_rn(qn, ksq), __fmul_rn(2.0f, dot));
    }
    __syncthreads();

    for (int i = tid; i < c2; i += 256) {
        const float di = sdf[i]; const int ni = sn[i];
        int rank = 0;
        for (int j = 0; j < c2; ++j) {
            const float dj = sdf[j]; const int nj = sn[j];
            rank += (dj < di || (dj == di && nj < ni)) ? 1 : 0;
        }
        if (rank < K_N) wn[rank] = ni;
    }
    __syncthreads();

    if (tid < K_N) {
        const int n = wn[tid];
        const float* kr = keys + ((size_t)a * N_N + n) * D_N;
        float r[8];
#pragma unroll
        for (int j = 0; j < 8; ++j) {
            float d = __fsub_rn(qrow[j], kr[j]);
            r[j] = __fmul_rn(d, d);
        }
        for (int i = 8; i < 64; i += 8)
#pragma unroll
            for (int j = 0; j < 8; ++j) {
                float d = __fsub_rn(qrow[i + j], kr[i + j]);
                r[j] = __fadd_rn(r[j], __fmul_rn(d, d));
            }
        const float dist = np_tree8(r);
        wsc[tid] = dist;
        wgv[tid] = values[(size_t)a * N_N + n];
        dout[OFF_IDX + (size_t)(b * A_N + a) * K_N + tid] = (float)n;
        dout[OFF_SC  + (size_t)(b * A_N + a) * K_N + tid] = dist;
    }
    __syncthreads();

    if (tid == 0) {
        float w[K_N], wv[K_N];
#pragma unroll
        for (int k = 0; k < K_N; ++k) {
            w[k]  = __fdiv_rn(1.0f, __fadd_rn(wsc[k], 0.001f));
            wv[k] = __fmul_rn(w[k], wgv[k]);
        }
        dout[OFF_VAL + b * A_N + a] = __fdiv_rn(np_sum50(wv), np_sum50(w));
    }
}

__global__ void dnd_k3(float* __restrict__ dout)
{
    const int b = threadIdx.x;
    float best = -__builtin_huge_valf(); int bi = 0;
#pragma unroll
    for (int a = 0; a < A_N; ++a) {
        const float v = dout[OFF_VAL + b * A_N + a];
        if (v > best) { best = v; bi = a; }
    }
    dout[OFF_MAX + b] = best;
    dout[OFF_ACT + b] = (float)bi;
}

// ===========================================================================
// FALLBACK PATH — R5 kernels verbatim (passed).
// ===========================================================================

__global__ __launch_bounds__(256)
void dnd_k0f(const float* __restrict__ query, const float* __restrict__ keys,
             float* __restrict__ qsq_g, float* __restrict__ ksq_g)
{
    const int r = blockIdx.x * 256 + threadIdx.x;
    if (r >= A_N * N_N + B_N) return;
    const bool isk = r < A_N * N_N;
    const float4* s4 = (const float4*)(isk ? (keys + (size_t)r * D_N)
                                           : (query + (size_t)(r - A_N * N_N) * D_N));
    float s = 0.f;
#pragma unroll
    for (int i = 0; i < 16; ++i) {
        float4 v = s4[i];
        s += v.x * v.x + v.y * v.y + v.z * v.z + v.w * v.w;
    }
    if (isk) ksq_g[r] = s; else qsq_g[r - A_N * N_N] = s;
}

__global__ __launch_bounds__(256, 4)
void dnd_k1f(const float* __restrict__ query, const float* __restrict__ keys,
             const float* __restrict__ qsq_g, const float* __restrict__ ksq_g,
             int* __restrict__ cnt, uint2* __restrict__ cand, int cap)
{
    __shared__ __align__(16) uint4 afrag[4][2][64];
    __shared__ __align__(16) uint4 bfrag[8][2][64];
    __shared__ float qsqs[QT];
    __shared__ float ksqs[NBT];

    const int a    = blockIdx.z;
    const int q0   = blockIdx.y * QT;
    const int sl   = blockIdx.x;
    const int tid  = threadIdx.x;
    const int lane = tid & 63;
    const int wave = tid >> 6;
    const int quad = lane >> 4;
    const int nl   = lane & 15;

    {
        const int r = tid & 63, seg = tid >> 6;
        const float4* s4 = (const float4*)(query + (size_t)(q0 + r) * D_N + seg * 16);
        float4 fv[4];
#pragma unroll
        for (int i = 0; i < 4; ++i) fv[i] = s4[i];
        const float* f = (const float*)fv;
        const int qtile = r >> 4, m = r & 15, kh = seg >> 1;
        const int quadA = (seg & 1) * 2;
        afrag[qtile][kh][quadA * 16 + m]       = packbf8(f);
        afrag[qtile][kh][(quadA + 1) * 16 + m] = packbf8(f + 8);
    }
    if (tid < QT) qsqs[tid] = qsq_g[q0 + tid];

    for (int t = sl; t < NT; t += SLF) {
        const int n0 = t * NBT;
        __syncthreads();
        {
            const int r = tid >> 1, h = tid & 1;
            int n = n0 + r; if (n > N_N - 1) n = N_N - 1;
            const float4* s4 = (const float4*)(keys + ((size_t)a * N_N + n) * D_N + h * 32);
            float4 fv[8];
#pragma unroll
            for (int i = 0; i < 8; ++i) fv[i] = s4[i];
            const float* f = (const float*)fv;
            const int s = r >> 4, m = r & 15;
#pragma unroll
            for (int g = 0; g < 4; ++g)
                bfrag[s][h][g * 16 + m] = packbf8(f + g * 8);
        }
        if (tid < NBT)
            ksqs[tid] = (n0 + tid < N_N) ? ksq_g[(size_t)a * N_N + n0 + tid]
                                         : __builtin_huge_valf();
        __syncthreads();

        const bf16x8 aA = ((const bf16x8*)afrag)[(wave * 2 + 0) * 64 + lane];
        const bf16x8 aB = ((const bf16x8*)afrag)[(wave * 2 + 1) * 64 + lane];

#pragma unroll
        for (int s = 0; s < 8; ++s) {
            const bf16x8 b0 = ((const bf16x8*)bfrag)[(s * 2 + 0) * 64 + lane];
            const bf16x8 b1 = ((const bf16x8*)bfrag)[(s * 2 + 1) * 64 + lane];
            f32x4 c = {0.f, 0.f, 0.f, 0.f};
            c = __builtin_amdgcn_mfma_f32_16x16x32_bf16(aA, b0, c, 0, 0, 0);
            c = __builtin_amdgcn_mfma_f32_16x16x32_bf16(aB, b1, c, 0, 0, 0);

            const int   nn  = n0 + s * 16 + nl;
            const float ksq = ksqs[s * 16 + nl];
#pragma unroll
            for (int r = 0; r < 4; ++r) {
                const int   qr = wave * 16 + quad * 4 + r;
                const float qq = qsqs[qr];
                const float d2 = qq + ksq - 2.0f * c[r];
                if (d2 <= qq + TMARG) {
                    const int b = q0 + qr;
                    const int p = atomicAdd(&cnt[a * B_N + b], 1);
                    if (p < cap) {
                        uint2 e; e.x = __float_as_uint(d2); e.y = (unsigned)nn;
                        cand[(size_t)(a * B_N + b) * cap + p] = e;
                    }
                }
            }
        }
    }
}

__global__ __launch_bounds__(256, 2)
void dnd_k2f(const float* __restrict__ query, const float* __restrict__ keys,
             const float* __restrict__ values,
             const int* __restrict__ cnt, const uint2* __restrict__ cand, int cap,
             float* __restrict__ dout)
{
    __shared__ __align__(16) float qrow[D_N];
    __shared__ float cd[CAPMAX];
    __shared__ int   cn[CAPMAX];
    __shared__ int   hist[256];
    __shared__ float sdf[512];
    __shared__ int   sn[512];
    __shared__ int   wn[K_N];
    __shared__ float wsc[K_N];
    __shared__ float wgv[K_N];
    __shared__ int   nsurv;
    __shared__ int   bstar;
    __shared__ float sqsq;
    __shared__ float qsq_np;

    const int b   = blockIdx.x;
    const int a   = blockIdx.y;
    const int ab  = a * B_N + b;
    const int tid = threadIdx.x;

    if (tid < D_N) qrow[tid] = query[(size_t)b * D_N + tid];
    hist[tid & 255] = 0;
    if (tid == 0) nsurv = 0;
    if (tid < K_N) wn[tid] = 0;
    __syncthreads();
    if (tid < 64) {
        float v = qrow[tid];
        float s = v * v;
#pragma unroll
        for (int m = 1; m < 64; m <<= 1) s += __shfl_xor(s, m, 64);
        if (tid == 0) sqsq = s;
    }
    if (tid == 0) qsq_np = np_sumsq64(qrow);
    __syncthreads();

    int c = cnt[ab]; if (c > cap) c = cap; if (c > CAPMAX) c = CAPMAX;
    const float qq = sqsq;

    for (int i = tid; i < c; i += 256) {
        uint2 e = cand[(size_t)ab * cap + i];
        float d = __uint_as_float(e.x);
        cd[i] = d; cn[i] = (int)e.y;
        int bin = (int)((d - qq + 40.f) * 4.f);
        bin = bin < 0 ? 0 : (bin > 255 ? 255 : bin);
        atomicAdd(&hist[bin], 1);
    }
    __syncthreads();
    if (tid == 0) {
        const int need = c < K_N ? c : K_N;
        int cum = 0, bs = 255;
        for (int i = 0; i < 256; ++i) { cum += hist[i]; if (cum >= need) { bs = i; break; } }
        bstar = bs;
    }
    __syncthreads();
    const int bs = bstar + 4;

    for (int i = tid; i < c; i += 256) {
        float d = cd[i];
        int bin = (int)((d - qq + 40.f) * 4.f);
        bin = bin < 0 ? 0 : (bin > 255 ? 255 : bin);
        if (bin <= bs) {
            int p = atomicAdd(&nsurv, 1);
            if (p < 512) sn[p] = cn[i];
        }
    }
    __syncthreads();
    int c2 = nsurv; if (c2 > 512) c2 = 512;

    const float qn = qsq_np;
    for (int i = tid; i < c2; i += 256) {
        const int n = sn[i];
        const float4* kr = (const float4*)(keys + ((size_t)a * N_N + n) * D_N);
        const float4* qr = (const float4*)qrow;
        float r[8];
#pragma unroll
        for (int j = 0; j < 8; ++j) r[j] = 0.f;
        float dot = 0.f;
#pragma unroll
        for (int cch = 0; cch < 16; ++cch) {
            float4 kk = kr[cch]; float4 qv = qr[cch];
            const int j0 = (cch & 1) * 4;
            if (cch < 2) {
                r[j0 + 0] = __fmul_rn(kk.x, kk.x);
                r[j0 + 1] = __fmul_rn(kk.y, kk.y);
                r[j0 + 2] = __fmul_rn(kk.z, kk.z);
                r[j0 + 3] = __fmul_rn(kk.w, kk.w);
            } else {
                r[j0 + 0] = __fadd_rn(r[j0 + 0], __fmul_rn(kk.x, kk.x));
                r[j0 + 1] = __fadd_rn(r[j0 + 1], __fmul_rn(kk.y, kk.y));
                r[j0 + 2] = __fadd_rn(r[j0 + 2], __fmul_rn(kk.z, kk.z));
                r[j0 + 3] = __fadd_rn(r[j0 + 3], __fmul_rn(kk.w, kk.w));
            }
            dot = __fmaf_rn(qv.x, kk.x, dot);
            dot = __fmaf_rn(qv.y, kk.y, dot);
            dot = __fmaf_rn(qv.z, kk.z, dot);
            dot = __fmaf_rn(qv.w, kk.w, dot);
        }
        const float ksq = np_tree8(r);
        sdf[i] = __fsub_rn(__fadd_rn(qn, ksq), __fmul_rn(2.0f, dot));
    }
    __syncthreads();

    for (int i = tid; i < c2; i += 256) {
        const float di = sdf[i]; const int ni = sn[i];
        int rank = 0;
        for (int j = 0; j < c2; ++j) {
            const float dj = sdf[j]; const int nj = sn[j];
            rank += (dj < di || (dj == di && nj < ni)) ? 1 : 0;
        }
        if (rank < K_N) wn[rank] = ni;
    }
    __syncthreads();

    if (tid < K_N) {
        const int n = wn[tid];
        const float* kr = keys + ((size_t)a * N_N + n) * D_N;
        float r[8];
#pragma unroll
        for (int j = 0; j < 8; ++j) {
            float d = __fsub_rn(qrow[j], kr[j]);
            r[j] = __fmul_rn(d, d);
        }
        for (int i = 8; i < 64; i += 8)
#pragma unroll
            for (int j = 0; j < 8; ++j) {
                float d = __fsub_rn(qrow[i + j], kr[i + j]);
                r[j] = __fadd_rn(r[j], __fmul_rn(d, d));
            }
        const float dist = np_tree8(r);
        wsc[tid] = dist;
        wgv[tid] = values[(size_t)a * N_N + n];
        dout[OFF_IDX + (size_t)(b * A_N + a) * K_N + tid] = (float)n;
        dout[OFF_SC  + (size_t)(b * A_N + a) * K_N + tid] = dist;
    }
    __syncthreads();

    if (tid == 0) {
        float w[K_N], wv[K_N];
#pragma unroll
        for (int k = 0; k < K_N; ++k) {
            w[k]  = __fdiv_rn(1.0f, __fadd_rn(wsc[k], 0.001f));
            wv[k] = __fmul_rn(w[k], wgv[k]);
        }
        dout[OFF_VAL + b * A_N + a] = __fdiv_rn(np_sum50(wv), np_sum50(w));
    }
}

// ===========================================================================
extern "C" void kernel_launch(void* const* d_in, const int* in_sizes, int n_in,
                              void* d_out, int out_size, void* d_ws, size_t ws_size,
                              hipStream_t stream)
{
    (void)in_sizes; (void)n_in; (void)out_size;
    const float* query  = (const float*)d_in[0];
    const float* keys   = (const float*)d_in[1];
    const float* values = (const float*)d_in[2];
    float* dout = (float*)d_out;
    char*  ws   = (char*)d_ws;

    long long capf = 0;
    if (ws_size > WSF_CAND)
        capf = (long long)((ws_size - WSF_CAND) / ((size_t)A_N * B_N * 4));
    const bool full = capf >= 3072;

    if (full) {
        int cap = capf > CAPMAX ? CAPMAX : (int)capf;
        int*      cnt  = (int*)(ws + WSF_CNT);
        float*    thrn = (float*)(ws + WSF_THR);
        uint4*    kbf  = (uint4*)(ws + WSF_KBF);
        unsigned* cand = (unsigned*)(ws + WSF_CAND);

        dim3 g0(NT, A_N);
        dnd_k0b<<<g0, 256, 0, stream>>>(keys, thrn, kbf, cnt);
        dim3 g1(SL, 4, A_N);
        dnd_k1<<<g1, 256, 0, stream>>>(query, kbf, thrn, cnt, cand, cap);
        dim3 g2(B_N, A_N);
        dnd_k2<<<g2, 256, 0, stream>>>(query, keys, values, cnt, cand, cap, dout);
        dnd_k3<<<1, 256, 0, stream>>>(dout);
    } else {
        int*   cnt   = (int*)(ws + WS_CNT);
        float* qsq_g = (float*)(ws + WS_QSQ);
        float* ksq_g = (float*)(ws + WS_KSQ);
        uint2* cand  = (uint2*)(ws + WS_CAND);
        int cap = CAPMAX;
        if (ws_size > WS_CAND) {
            size_t avail = (ws_size - WS_CAND) / ((size_t)A_N * B_N * 8);
            if ((size_t)cap > avail) cap = (int)avail;
        }
        if (cap < 1) cap = 1;

        hipMemsetAsync(cnt, 0, A_N * B_N * sizeof(int), stream);
        dnd_k0f<<<(A_N * N_N + B_N + 255) / 256, 256, 0, stream>>>(query, keys, qsq_g, ksq_g);
        dim3 g1(SLF, 4, A_N);
        dnd_k1f<<<g1, 256, 0, stream>>>(query, keys, qsq_g, ksq_g, cnt, cand, cap);
        dim3 g2(B_N, A_N);
        dnd_k2f<<<g2, 256, 0, stream>>>(query, keys, values, cnt, cand, cap, dout);
        dnd_k3<<<1, 256, 0, stream>>>(dout);
    }
}